// Round 13
// baseline (73.390 us; speedup 1.0000x reference)
//
#include <hip/hip_runtime.h>
#include <math.h>

// PWNet3DH2O via exact-structure tabulation (v4).
// out(b,l) = tanh(s_g(r)+bl) / (r^3+0.1); s_g(r) piecewise-linear in r.
// Kernel A (build_table_mfma): one wg per (g, 64-entry chunk); W2 -> fp16
// A-frags, h1 per-lane f32 -> fp16 B-frags, 16x16x32 MFMA, f32 epilogue.
// Kernel B (apply_table4): 4 columns/thread, float4 loads/stores, lerp +
// exact 1/(r^3+eps). T=2048 (interp err ~1e-4 << bf16 output ULP).
// Measured floor context (R11): harness re-poison of d_ws (268MB, ~41.5us @81%
// HBM) + restores ~= 62us constant inside the timed path; our kernels ~10us.

typedef _Float16 f16x8 __attribute__((ext_vector_type(8)));
typedef float f32x4 __attribute__((ext_vector_type(4)));

#define TCH 64   // table entries per workgroup

union H8 { f16x8 v; _Float16 h[8]; };

// ---------------- Kernel A: MFMA table build ----------------
__global__ __launch_bounds__(256, 2) void build_table_mfma(
    const float* __restrict__ W1, const float* __restrict__ b1,
    const float* __restrict__ W2, const float* __restrict__ b2,
    const float* __restrict__ Wl, const float* __restrict__ bl,
    float* __restrict__ table, int T, int chunks)
{
    __shared__ float W1s[128], b1s[128];
    __shared__ float red[4][TCH][3];     // [wave][entry][o3], 3 KB

    const int tid  = threadIdx.x;
    const int wave = tid >> 6, lane = tid & 63;
    const int lo   = lane & 15, hi = lane >> 4;
    const int wrow = wave * 32;
    const int g     = blockIdx.x / chunks;
    const int chunk = blockIdx.x % chunks;
    const int e0    = chunk * TCH;
    const float hstep = 1.5f / (float)T;

    if (tid < 128) {
        W1s[tid] = W1[g*128 + tid];
        b1s[tid] = b1[g*128 + tid];
    }

    // A-frags: lane holds W2[row = wrow+mf*16+lo][k = ks*32+hi*8+j] (R5-verified)
    f16x8 A[2][4];
#pragma unroll
    for (int mf = 0; mf < 2; ++mf)
#pragma unroll
        for (int ks = 0; ks < 4; ++ks) {
            const float* p = W2 + ((g*128 + wrow + mf*16 + lo)*128 + ks*32 + hi*8);
            float4 f0 = *(const float4*)p;
            float4 f1 = *(const float4*)(p + 4);
            f16x8 a;
            a[0] = (_Float16)f0.x; a[1] = (_Float16)f0.y;
            a[2] = (_Float16)f0.z; a[3] = (_Float16)f0.w;
            a[4] = (_Float16)f1.x; a[5] = (_Float16)f1.y;
            a[6] = (_Float16)f1.z; a[7] = (_Float16)f1.w;
            A[mf][ks] = a;
        }
    __syncthreads();

    // GEMM: h2[128 x 64] = W2 @ relu(W1*r + b1), entries e = nf*16 + lo
    f32x4 acc[2][4];
#pragma unroll
    for (int mf = 0; mf < 2; ++mf)
#pragma unroll
        for (int nf = 0; nf < 4; ++nf)
            acc[mf][nf] = (f32x4){0.f, 0.f, 0.f, 0.f};

#pragma unroll
    for (int ks = 0; ks < 4; ++ks) {
        const int k0 = ks*32 + hi*8;
        float4 wA = *(const float4*)&W1s[k0];
        float4 wB = *(const float4*)&W1s[k0 + 4];
        float4 bA = *(const float4*)&b1s[k0];
        float4 bB = *(const float4*)&b1s[k0 + 4];
#pragma unroll
        for (int nf = 0; nf < 4; ++nf) {
            const float r = fmaf((float)(e0 + nf*16 + lo), hstep, 0.5f);
            H8 bb;   // B-frag: lane holds h1[k = ks*32+hi*8+j] for col nf*16+lo
            bb.h[0] = (_Float16)fmaxf(fmaf(wA.x, r, bA.x), 0.f);
            bb.h[1] = (_Float16)fmaxf(fmaf(wA.y, r, bA.y), 0.f);
            bb.h[2] = (_Float16)fmaxf(fmaf(wA.z, r, bA.z), 0.f);
            bb.h[3] = (_Float16)fmaxf(fmaf(wA.w, r, bA.w), 0.f);
            bb.h[4] = (_Float16)fmaxf(fmaf(wB.x, r, bB.x), 0.f);
            bb.h[5] = (_Float16)fmaxf(fmaf(wB.y, r, bB.y), 0.f);
            bb.h[6] = (_Float16)fmaxf(fmaf(wB.z, r, bB.z), 0.f);
            bb.h[7] = (_Float16)fmaxf(fmaf(wB.w, r, bB.w), 0.f);
            acc[0][nf] = __builtin_amdgcn_mfma_f32_16x16x32_f16(A[0][ks], bb.v, acc[0][nf], 0, 0, 0);
            acc[1][nf] = __builtin_amdgcn_mfma_f32_16x16x32_f16(A[1][ks], bb.v, acc[1][nf], 0, 0, 0);
        }
    }

    // Epilogue (f32): C-frag row = wrow + mf*16 + hi*4 + q, col = lo (R5-verified)
    const float4 bq0 = *(const float4*)&b2[g*128 + wrow + hi*4];
    const float4 bq1 = *(const float4*)&b2[g*128 + wrow + 16 + hi*4];
    float4 wl[3][2];
#pragma unroll
    for (int o = 0; o < 3; ++o) {
        wl[o][0] = *(const float4*)&Wl[o*384 + g*128 + wrow + hi*4];
        wl[o][1] = *(const float4*)&Wl[o*384 + g*128 + wrow + 16 + hi*4];
    }

    float p[4][3];
#pragma unroll
    for (int nf = 0; nf < 4; ++nf) {
        float h00 = fmaxf(acc[0][nf][0] + bq0.x, 0.f);
        float h01 = fmaxf(acc[0][nf][1] + bq0.y, 0.f);
        float h02 = fmaxf(acc[0][nf][2] + bq0.z, 0.f);
        float h03 = fmaxf(acc[0][nf][3] + bq0.w, 0.f);
        float h10 = fmaxf(acc[1][nf][0] + bq1.x, 0.f);
        float h11 = fmaxf(acc[1][nf][1] + bq1.y, 0.f);
        float h12 = fmaxf(acc[1][nf][2] + bq1.z, 0.f);
        float h13 = fmaxf(acc[1][nf][3] + bq1.w, 0.f);
#pragma unroll
        for (int o = 0; o < 3; ++o) {
            float s;
            s  = h00 * wl[o][0].x;
            s  = fmaf(h01, wl[o][0].y, s);
            s  = fmaf(h02, wl[o][0].z, s);
            s  = fmaf(h03, wl[o][0].w, s);
            s  = fmaf(h10, wl[o][1].x, s);
            s  = fmaf(h11, wl[o][1].y, s);
            s  = fmaf(h12, wl[o][1].z, s);
            s  = fmaf(h13, wl[o][1].w, s);
            p[nf][o] = s;
        }
    }
    // reduce over hi-groups (entry index lo preserved)
#pragma unroll
    for (int nf = 0; nf < 4; ++nf)
#pragma unroll
        for (int o = 0; o < 3; ++o) {
            p[nf][o] += __shfl_xor(p[nf][o], 16, 64);
            p[nf][o] += __shfl_xor(p[nf][o], 32, 64);
        }
    if (hi == 0) {
#pragma unroll
        for (int nf = 0; nf < 4; ++nf)
#pragma unroll
            for (int o = 0; o < 3; ++o)
                red[wave][nf*16 + lo][o] = p[nf][o];
    }
    __syncthreads();

    if (tid < 192) {                   // 64 entries x 3 outputs
        int e = tid / 3, o = tid - e*3;
        if (e0 + e <= T) {
            float s = red[0][e][o] + red[1][e][o] + red[2][e][o] + red[3][e][o];
            float v = tanhf(s + bl[o]);
            table[(size_t)(g*(T+1) + e0 + e)*4 + o] = v;
        }
    }
}

// ---------------- Kernel B: 4 columns per thread, float4 I/O ----------------
__global__ __launch_bounds__(256) void apply_table4(
    const float* __restrict__ x, const float4* __restrict__ table,
    float* __restrict__ out, int ncols4, int T, float scaleT)
{
    int t = blockIdx.x*256 + threadIdx.x;
    if (t >= ncols4) return;
    const int b  = t >> 2;
    const int l0 = (t & 3) * 4;
    const int base = b*48 + l0;

    float a0[4], a1[4], a2[4];
    *(float4*)a0 = *(const float4*)(x + base);
    *(float4*)a1 = *(const float4*)(x + base + 16);
    *(float4*)a2 = *(const float4*)(x + base + 32);

    float o0[4], o1[4], o2[4];
#pragma unroll
    for (int j = 0; j < 4; ++j) {
        float r = a0[j] + a1[j] + a2[j];
        int   g = (a0[j] > 1e-6f) ? 0 : ((a1[j] > 1e-6f) ? 1 : 2);

        float u = (r - 0.5f) * scaleT;
        u = fminf(fmaxf(u, 0.0f), (float)T);
        int i = (int)u;
        if (i > T - 1) i = T - 1;
        float f = u - (float)i;

        float4 t0 = table[g*(T+1) + i];
        float4 t1 = table[g*(T+1) + i + 1];
        float w = 1.0f / (r*r*r + 0.1f);

        o0[j] = fmaf(f, t1.x - t0.x, t0.x) * w;
        o1[j] = fmaf(f, t1.y - t0.y, t0.y) * w;
        o2[j] = fmaf(f, t1.z - t0.z, t0.z) * w;
    }
    *(float4*)(out + base)      = *(const float4*)o0;
    *(float4*)(out + base + 16) = *(const float4*)o1;
    *(float4*)(out + base + 32) = *(const float4*)o2;
}

// ---------------- Safety fallback: direct per-column compute ----------------
__global__ __launch_bounds__(256, 2) void pwnet_direct(
    const float* __restrict__ x,  const float* __restrict__ W1,
    const float* __restrict__ b1, const float* __restrict__ W2,
    const float* __restrict__ b2, const float* __restrict__ Wl,
    const float* __restrict__ bl, float* __restrict__ out, int ncols)
{
    int t = blockIdx.x * blockDim.x + threadIdx.x;
    if (t >= ncols) return;
    int base = (t >> 4) * 48 + (t & 15);

    float x0 = x[base], x1 = x[base + 16], x2 = x[base + 32];
    float r = x0 + x1 + x2;
    int   g = (x0 > 1e-6f) ? 0 : ((x1 > 1e-6f) ? 1 : 2);

    float h1[128];
    const float4* W1v = (const float4*)(W1 + g*128);
    const float4* b1v = (const float4*)(b1 + g*128);
#pragma unroll
    for (int i = 0; i < 32; ++i) {
        float4 wv = W1v[i], bv = b1v[i];
        h1[4*i+0] = fmaxf(fmaf(wv.x, r, bv.x), 0.f);
        h1[4*i+1] = fmaxf(fmaf(wv.y, r, bv.y), 0.f);
        h1[4*i+2] = fmaxf(fmaf(wv.z, r, bv.z), 0.f);
        h1[4*i+3] = fmaxf(fmaf(wv.w, r, bv.w), 0.f);
    }
    const float* W2g = W2 + g*128*128;
    const float* b2g = b2 + g*128;
    const float* Wlg = Wl + g*128;
    float acc0 = 0.f, acc1 = 0.f, acc2 = 0.f;
#pragma unroll 2
    for (int o = 0; o < 128; ++o) {
        const float4* wrow = (const float4*)(W2g + o*128);
        float s0 = b2g[o], s1 = 0.f, s2 = 0.f, s3 = 0.f;
#pragma unroll
        for (int i = 0; i < 32; ++i) {
            float4 wv = wrow[i];
            s0 = fmaf(wv.x, h1[4*i+0], s0);
            s1 = fmaf(wv.y, h1[4*i+1], s1);
            s2 = fmaf(wv.z, h1[4*i+2], s2);
            s3 = fmaf(wv.w, h1[4*i+3], s3);
        }
        float h2 = fmaxf((s0+s1)+(s2+s3), 0.f);
        acc0 = fmaf(Wlg[o],       h2, acc0);
        acc1 = fmaf(Wlg[384 + o], h2, acc1);
        acc2 = fmaf(Wlg[768 + o], h2, acc2);
    }
    float w = 1.0f / (r*r*r + 0.1f);
    out[base]      = tanhf(acc0 + bl[0]) * w;
    out[base + 16] = tanhf(acc1 + bl[1]) * w;
    out[base + 32] = tanhf(acc2 + bl[2]) * w;
}

extern "C" void kernel_launch(void* const* d_in, const int* in_sizes, int n_in,
                              void* d_out, int out_size, void* d_ws, size_t ws_size,
                              hipStream_t stream) {
    const float* x  = (const float*)d_in[0];
    const float* W1 = (const float*)d_in[1];
    const float* b1 = (const float*)d_in[2];
    const float* W2 = (const float*)d_in[3];
    const float* b2 = (const float*)d_in[4];
    const float* Wl = (const float*)d_in[5];
    const float* bl = (const float*)d_in[6];
    float* out = (float*)d_out;
    int ncols = in_sizes[0] / 3;   // B * L

    // largest table size that fits the workspace, capped at 2048
    int T = 0;
    for (int cand = 2048; cand >= 64; cand >>= 1) {
        if ((size_t)(3 * (cand + 1) * 16) <= ws_size) { T = cand; break; }
    }

    if (T == 0 || d_ws == nullptr) {
        pwnet_direct<<<(ncols + 255)/256, 256, 0, stream>>>(
            x, W1, b1, W2, b2, Wl, bl, out, ncols);
        return;
    }

    int chunks = (T + 1 + TCH - 1) / TCH;
    build_table_mfma<<<3 * chunks, 256, 0, stream>>>(
        W1, b1, W2, b2, Wl, bl, (float*)d_ws, T, chunks);
    int ncols4 = ncols >> 2;
    apply_table4<<<(ncols4 + 255)/256, 256, 0, stream>>>(
        x, (const float4*)d_ws, out, ncols4, T, (float)T / 1.5f);
}